// Round 1
// baseline (147.623 us; speedup 1.0000x reference)
//
#include <hip/hip_runtime.h>
#include <hip/hip_bf16.h>
#include <math.h>

// Problem: AttentionDecoder — Bahdanau attention + 1-step LSTM + out proj.
// SEQ=4096, H=2048, NF=512. All f32 in/out.

#define HIDDEN 2048
#define SEQL   4096
#define NFEAT  512

typedef __attribute__((ext_vector_type(8))) short frag_t;   // 8 bf16
typedef __attribute__((ext_vector_type(4))) float f32x4;

__device__ __forceinline__ unsigned short f2bf(float f) {
    union { float f; unsigned int u; } c; c.f = f;
    unsigned int r = c.u + 0x7fffu + ((c.u >> 16) & 1u);   // RNE
    return (unsigned short)(r >> 16);
}

__device__ __forceinline__ float wave_sum(float s) {
    #pragma unroll
    for (int off = 32; off; off >>= 1) s += __shfl_down(s, off);
    return s;
}

// ---------------------------------------------------------------------------
// K1: h_pre[h] = b_attn[h] + W_attn[h, 0:2048] @ h0          (rows 0..2047)
//     gates[j] = b_ih+b_hh + W_ih[j,0:512]@x + W_hh[j]@h0    (rows 2048..10239)
// one wave per row
__global__ __launch_bounds__(256)
void k_pre_gemv(const float* __restrict__ Wattn, const float* __restrict__ b_attn,
                const float* __restrict__ Wih,  const float* __restrict__ Whh,
                const float* __restrict__ b_ih, const float* __restrict__ b_hh,
                const float* __restrict__ x,    const float* __restrict__ h0,
                float* __restrict__ h_pre, float* __restrict__ gates)
{
    const int gw = (blockIdx.x * 256 + threadIdx.x) >> 6;
    const int lane = threadIdx.x & 63;
    if (gw < HIDDEN) {
        const float* Wr = Wattn + (size_t)gw * 4096;
        float s = 0.f;
        #pragma unroll
        for (int i = 0; i < 8; i++) {
            int c = i * 256 + lane * 4;
            float4 wv = *reinterpret_cast<const float4*>(Wr + c);
            float4 hv = *reinterpret_cast<const float4*>(h0 + c);
            s += wv.x*hv.x + wv.y*hv.y + wv.z*hv.z + wv.w*hv.w;
        }
        s = wave_sum(s);
        if (lane == 0) h_pre[gw] = s + b_attn[gw];
    } else {
        const int j = gw - HIDDEN;
        const float* W1 = Wih + (size_t)j * 2560;        // x part (cols 0..511)
        const float* W2 = Whh + (size_t)j * 2048;
        float s = 0.f;
        #pragma unroll
        for (int i = 0; i < 2; i++) {
            int c = i * 256 + lane * 4;
            float4 wv = *reinterpret_cast<const float4*>(W1 + c);
            float4 xv = *reinterpret_cast<const float4*>(x + c);
            s += wv.x*xv.x + wv.y*xv.y + wv.z*xv.z + wv.w*xv.w;
        }
        #pragma unroll
        for (int i = 0; i < 8; i++) {
            int c = i * 256 + lane * 4;
            float4 wv = *reinterpret_cast<const float4*>(W2 + c);
            float4 hv = *reinterpret_cast<const float4*>(h0 + c);
            s += wv.x*hv.x + wv.y*hv.y + wv.z*hv.z + wv.w*hv.w;
        }
        s = wave_sum(s);
        if (lane == 0) gates[j] = s + b_ih[j] + b_hh[j];
    }
}

// ---------------------------------------------------------------------------
// K2: fused energy GEMM + tanh + v-dot reduction.
// C[s,h] = sum_k enc[s,k] * Wattn[h, 2048+k]   (NT gemm, bf16 MFMA, f32 acc)
// pscore[hb][s] = sum_{h in tile hb} tanh(C[s,h] + h_pre[h]) * v[h]
// 128x128 tile, BK=32, 4 waves (2x2), 4x4 16x16x32 frags per wave.
#define LROW 40   // LDS row pitch in bf16 elems (32 + 8 pad -> 2-way-free banks)

__global__ __launch_bounds__(256)
void k_energy(const float* __restrict__ enc, const float* __restrict__ Wattn,
              const float* __restrict__ h_pre, const float* __restrict__ v_attn,
              float* __restrict__ pscore)
{
    __shared__ __align__(16) unsigned short As[128 * LROW];
    __shared__ __align__(16) unsigned short Bs[128 * LROW];
    __shared__ float sh_hv[2][128];
    __shared__ float sh_part[2][128];

    const int tid = threadIdx.x;
    const int hb = blockIdx.x;        // 0..15  (h tiles)
    const int sb = blockIdx.y;        // 0..31  (s tiles)
    const int s0 = sb * 128, h0 = hb * 128;
    const int wv = tid >> 6, lane = tid & 63;
    const int wm = wv >> 1, wn = wv & 1;

    f32x4 acc[4][4];
    #pragma unroll
    for (int m = 0; m < 4; m++)
        #pragma unroll
        for (int n = 0; n < 4; n++)
            acc[m][n] = (f32x4){0.f, 0.f, 0.f, 0.f};

    for (int kt = 0; kt < 2048; kt += 32) {
        __syncthreads();   // WAR: previous iter's ds_reads done before overwrite
        #pragma unroll
        for (int i = 0; i < 4; i++) {
            const int flat = i * 256 + tid;        // 1024 float4 per tile
            const int row = flat >> 3, c4 = flat & 7;
            float4 av = *reinterpret_cast<const float4*>(
                enc + (size_t)(s0 + row) * 2048 + kt + c4 * 4);
            *reinterpret_cast<ushort4*>(&As[row * LROW + c4 * 4]) =
                make_ushort4(f2bf(av.x), f2bf(av.y), f2bf(av.z), f2bf(av.w));
            float4 bv = *reinterpret_cast<const float4*>(
                Wattn + (size_t)(h0 + row) * 4096 + 2048 + kt + c4 * 4);
            *reinterpret_cast<ushort4*>(&Bs[row * LROW + c4 * 4]) =
                make_ushort4(f2bf(bv.x), f2bf(bv.y), f2bf(bv.z), f2bf(bv.w));
        }
        __syncthreads();
        frag_t af[4], bf[4];
        #pragma unroll
        for (int m = 0; m < 4; m++)
            af[m] = *reinterpret_cast<const frag_t*>(
                &As[(wm * 64 + m * 16 + (lane & 15)) * LROW + (lane >> 4) * 8]);
        #pragma unroll
        for (int n = 0; n < 4; n++)
            bf[n] = *reinterpret_cast<const frag_t*>(
                &Bs[(wn * 64 + n * 16 + (lane & 15)) * LROW + (lane >> 4) * 8]);
        #pragma unroll
        for (int m = 0; m < 4; m++)
            #pragma unroll
            for (int n = 0; n < 4; n++)
                acc[m][n] = __builtin_amdgcn_mfma_f32_16x16x32_bf16(
                    af[m], bf[n], acc[m][n], 0, 0, 0);
    }

    if (tid < 128) { sh_hv[0][tid] = h_pre[h0 + tid]; sh_hv[1][tid] = v_attn[h0 + tid]; }
    __syncthreads();

    // epilogue: tanh + *v, reduce over h (cols) within the tile
    float ps[4][4];
    #pragma unroll
    for (int m = 0; m < 4; m++)
        #pragma unroll
        for (int r = 0; r < 4; r++) ps[m][r] = 0.f;

    #pragma unroll
    for (int m = 0; m < 4; m++) {
        #pragma unroll
        for (int n = 0; n < 4; n++) {
            const int hc = wn * 64 + n * 16 + (lane & 15);
            const float hp = sh_hv[0][hc], vv = sh_hv[1][hc];
            #pragma unroll
            for (int r = 0; r < 4; r++) {
                float e = tanhf(acc[m][n][r] + hp);
                ps[m][r] += e * vv;
            }
        }
    }
    // reduce across the 16 cols (lane&15) of each group
    #pragma unroll
    for (int m = 0; m < 4; m++)
        #pragma unroll
        for (int r = 0; r < 4; r++) {
            float p = ps[m][r];
            #pragma unroll
            for (int off = 1; off < 16; off <<= 1) p += __shfl_xor(p, off);
            ps[m][r] = p;
        }
    if ((lane & 15) == 0) {
        const int grp = lane >> 4;
        #pragma unroll
        for (int m = 0; m < 4; m++)
            #pragma unroll
            for (int r = 0; r < 4; r++)
                sh_part[wn][wm * 64 + m * 16 + grp * 4 + r] = ps[m][r];
    }
    __syncthreads();
    if (tid < 128)
        pscore[hb * SEQL + s0 + tid] = sh_part[0][tid] + sh_part[1][tid];
}

// ---------------------------------------------------------------------------
// K3: reduce 16 partial score tiles + softmax over 4096 (one block)
__global__ __launch_bounds__(1024)
void k_softmax(const float* __restrict__ pscore, float* __restrict__ attnw)
{
    __shared__ float red[16];
    __shared__ float bcast;
    const int t = threadIdx.x, wv = t >> 6, lane = t & 63;
    float s[4];
    #pragma unroll
    for (int q = 0; q < 4; q++) {
        const int idx = q * 1024 + t;
        float a = 0.f;
        #pragma unroll
        for (int p = 0; p < 16; p++) a += pscore[p * SEQL + idx];
        s[q] = a;
    }
    float mx = fmaxf(fmaxf(s[0], s[1]), fmaxf(s[2], s[3]));
    #pragma unroll
    for (int off = 32; off; off >>= 1) mx = fmaxf(mx, __shfl_xor(mx, off));
    if (!lane) red[wv] = mx;
    __syncthreads();
    if (t == 0) {
        float m = red[0];
        for (int i = 1; i < 16; i++) m = fmaxf(m, red[i]);
        bcast = m;
    }
    __syncthreads();
    const float bm = bcast;
    float e[4], sum = 0.f;
    #pragma unroll
    for (int q = 0; q < 4; q++) { e[q] = __expf(s[q] - bm); sum += e[q]; }
    #pragma unroll
    for (int off = 32; off; off >>= 1) sum += __shfl_xor(sum, off);
    __syncthreads();
    if (!lane) red[wv] = sum;
    __syncthreads();
    if (t == 0) {
        float m = 0.f;
        for (int i = 0; i < 16; i++) m += red[i];
        bcast = m;
    }
    __syncthreads();
    const float inv = 1.f / bcast;
    #pragma unroll
    for (int q = 0; q < 4; q++) attnw[q * 1024 + t] = e[q] * inv;
}

// ---------------------------------------------------------------------------
// K4: weighted partials: pweight[sb][h] = sum_{s in 64-chunk sb} a[s]*enc[s,h]
__global__ __launch_bounds__(256)
void k_weighted_part(const float* __restrict__ enc, const float* __restrict__ attnw,
                     float* __restrict__ pweight)
{
    const int hb = blockIdx.x & 7, sbk = blockIdx.x >> 3;   // 8 x 64 blocks
    const int h = hb * 256 + threadIdx.x;
    const int sbase = sbk * 64;
    float acc = 0.f;
    for (int s = 0; s < 64; s++)
        acc += attnw[sbase + s] * enc[(size_t)(sbase + s) * HIDDEN + h];
    pweight[sbk * HIDDEN + h] = acc;
}

// K5: reduce 64 partials -> weighted[2048]
__global__ __launch_bounds__(256)
void k_weighted_reduce(const float* __restrict__ pweight, float* __restrict__ weighted)
{
    const int h = blockIdx.x * 256 + threadIdx.x;
    float acc = 0.f;
    #pragma unroll 8
    for (int sb = 0; sb < 64; sb++) acc += pweight[sb * HIDDEN + h];
    weighted[h] = acc;
}

// ---------------------------------------------------------------------------
// K6: gates[j] += W_ih[j, 512:2560] @ weighted   (one wave per row)
__global__ __launch_bounds__(256)
void k_gates_fin(const float* __restrict__ Wih, const float* __restrict__ weighted,
                 float* __restrict__ gates)
{
    const int j = (blockIdx.x * 256 + threadIdx.x) >> 6;
    const int lane = threadIdx.x & 63;
    const float* Wr = Wih + (size_t)j * 2560 + 512;
    float s = 0.f;
    #pragma unroll
    for (int i = 0; i < 8; i++) {
        int c = i * 256 + lane * 4;
        float4 wv = *reinterpret_cast<const float4*>(Wr + c);
        float4 hv = *reinterpret_cast<const float4*>(weighted + c);
        s += wv.x*hv.x + wv.y*hv.y + wv.z*hv.z + wv.w*hv.w;
    }
    s = wave_sum(s);
    if (lane == 0) gates[j] += s;
}

// ---------------------------------------------------------------------------
// K7: LSTM elementwise. gate order i,f,g,o. writes h_n, c_n into d_out.
__global__ __launch_bounds__(256)
void k_lstm(const float* __restrict__ gates, const float* __restrict__ c0,
            float* __restrict__ dout)
{
    const int t = blockIdx.x * 256 + threadIdx.x;   // 0..2047
    const float gi = gates[t];
    const float gf = gates[2048 + t];
    const float gg = gates[4096 + t];
    const float go = gates[6144 + t];
    const float si = 1.f / (1.f + __expf(-gi));
    const float sf = 1.f / (1.f + __expf(-gf));
    const float so = 1.f / (1.f + __expf(-go));
    const float c = sf * c0[t] + si * tanhf(gg);
    const float h = so * tanhf(c);
    dout[512 + t]  = h;          // h_n
    dout[2560 + t] = c;          // c_n
}

// ---------------------------------------------------------------------------
// K8: out[n] = b_out[n] + W_out[n,0:2048]@h_n + W_out[n,2048:4096]@weighted
__global__ __launch_bounds__(256)
void k_out_gemv(const float* __restrict__ Wout, const float* __restrict__ b_out,
                const float* __restrict__ hn, const float* __restrict__ weighted,
                float* __restrict__ dout)
{
    const int n = (blockIdx.x * 256 + threadIdx.x) >> 6;   // 0..511
    const int lane = threadIdx.x & 63;
    const float* Wr = Wout + (size_t)n * 4096;
    float s = 0.f;
    #pragma unroll
    for (int i = 0; i < 8; i++) {
        int c = i * 256 + lane * 4;
        float4 wv = *reinterpret_cast<const float4*>(Wr + c);
        float4 hv = *reinterpret_cast<const float4*>(hn + c);
        s += wv.x*hv.x + wv.y*hv.y + wv.z*hv.z + wv.w*hv.w;
        float4 wv2 = *reinterpret_cast<const float4*>(Wr + 2048 + c);
        float4 hv2 = *reinterpret_cast<const float4*>(weighted + c);
        s += wv2.x*hv2.x + wv2.y*hv2.y + wv2.z*hv2.z + wv2.w*hv2.w;
    }
    s = wave_sum(s);
    if (lane == 0) dout[n] = s + b_out[n];
}

// ---------------------------------------------------------------------------
extern "C" void kernel_launch(void* const* d_in, const int* in_sizes, int n_in,
                              void* d_out, int out_size, void* d_ws, size_t ws_size,
                              hipStream_t stream)
{
    const float* x        = (const float*)d_in[0];
    const float* ih       = (const float*)d_in[1];   // input_hidden [1,1,2048]
    const float* ic       = (const float*)d_in[2];   // input_cell
    const float* enc      = (const float*)d_in[3];   // [4096,2048]
    const float* Wattn    = (const float*)d_in[4];   // [2048,4096]
    const float* b_attn   = (const float*)d_in[5];
    const float* v_attn   = (const float*)d_in[6];
    const float* Wih      = (const float*)d_in[7];   // [8192,2560]
    const float* Whh      = (const float*)d_in[8];   // [8192,2048]
    const float* b_ih     = (const float*)d_in[9];
    const float* b_hh     = (const float*)d_in[10];
    const float* Wout     = (const float*)d_in[11];  // [512,4096]
    const float* b_out    = (const float*)d_in[12];
    float* dout = (float*)d_out;   // [out 512][h_n 2048][c_n 2048]

    float* ws       = (float*)d_ws;
    float* h_pre    = ws;                 // 2048
    float* gates    = ws + 2048;          // 8192
    float* pscore   = ws + 10240;         // 16*4096
    float* attnw    = ws + 75776;         // 4096
    float* pweight  = ws + 79872;         // 64*2048
    float* weighted = ws + 210944;        // 2048

    k_pre_gemv<<<2560, 256, 0, stream>>>(Wattn, b_attn, Wih, Whh, b_ih, b_hh,
                                         x, ih, h_pre, gates);
    k_energy<<<dim3(16, 32), 256, 0, stream>>>(enc, Wattn, h_pre, v_attn, pscore);
    k_softmax<<<1, 1024, 0, stream>>>(pscore, attnw);
    k_weighted_part<<<512, 256, 0, stream>>>(enc, attnw, pweight);
    k_weighted_reduce<<<8, 256, 0, stream>>>(pweight, weighted);
    k_gates_fin<<<2048, 256, 0, stream>>>(Wih, weighted, gates);
    k_lstm<<<8, 256, 0, stream>>>(gates, ic, dout);
    k_out_gemv<<<128, 256, 0, stream>>>(Wout, b_out, dout + 512, weighted, dout);
}

// Round 2
// 109.496 us; speedup vs baseline: 1.3482x; 1.3482x over previous
//
#include <hip/hip_runtime.h>
#include <hip/hip_bf16.h>
#include <math.h>

// AttentionDecoder — Bahdanau attention + 1-step LSTM + out proj.
// SEQ=4096, H=2048, NF=512. All f32 in/out.
//
// R2: pre-convert enc / W_attn-right-half to bf16 in ws; energy GEMM now
// m97-structure (BK=64, global_load_lds width=16, XOR-swizzled LDS via
// pre-swizzled per-lane global source, linear LDS dest).

#define HIDDEN 2048
#define SEQL   4096
#define NFEAT  512

typedef __attribute__((ext_vector_type(8))) short frag_t;   // 8 bf16
typedef __attribute__((ext_vector_type(8))) unsigned short u16x8;
typedef __attribute__((ext_vector_type(4))) float f32x4;

__device__ __forceinline__ unsigned short f2bf(float f) {
    union { float f; unsigned int u; } c; c.f = f;
    unsigned int r = c.u + 0x7fffu + ((c.u >> 16) & 1u);   // RNE
    return (unsigned short)(r >> 16);
}

__device__ __forceinline__ float wave_sum(float s) {
    #pragma unroll
    for (int off = 32; off; off >>= 1) s += __shfl_down(s, off);
    return s;
}

__device__ __forceinline__ void gload16(const unsigned short* g, unsigned short* l) {
    __builtin_amdgcn_global_load_lds(
        (const __attribute__((address_space(1))) unsigned int*)g,
        (__attribute__((address_space(3))) unsigned int*)l, 16, 0, 0);
}

// ---------------------------------------------------------------------------
// K0: f32 -> bf16 convert. blocks 0..4095: enc rows; 4096..6143: Wattn rows
// (cols 2048..4095 only). One block per row, 8 elems/thread.
__global__ __launch_bounds__(256)
void k_conv(const float* __restrict__ enc, const float* __restrict__ Wattn,
            unsigned short* __restrict__ encbf, unsigned short* __restrict__ wbf)
{
    const int b = blockIdx.x;
    const float* src;
    unsigned short* dst;
    if (b < 4096) {
        src = enc + (size_t)b * 2048;
        dst = encbf + (size_t)b * 2048;
    } else {
        const int r = b - 4096;
        src = Wattn + (size_t)r * 4096 + 2048;
        dst = wbf + (size_t)r * 2048;
    }
    const int t = threadIdx.x;
    float4 a = *reinterpret_cast<const float4*>(src + t * 8);
    float4 c = *reinterpret_cast<const float4*>(src + t * 8 + 4);
    u16x8 o;
    o[0] = f2bf(a.x); o[1] = f2bf(a.y); o[2] = f2bf(a.z); o[3] = f2bf(a.w);
    o[4] = f2bf(c.x); o[5] = f2bf(c.y); o[6] = f2bf(c.z); o[7] = f2bf(c.w);
    *reinterpret_cast<u16x8*>(dst + t * 8) = o;
}

// ---------------------------------------------------------------------------
// K1: h_pre[h] = b_attn[h] + W_attn[h, 0:2048] @ h0          (rows 0..2047)
//     gates[j] = b_ih+b_hh + W_ih[j,0:512]@x + W_hh[j]@h0    (rows 2048..10239)
__global__ __launch_bounds__(256)
void k_pre_gemv(const float* __restrict__ Wattn, const float* __restrict__ b_attn,
                const float* __restrict__ Wih,  const float* __restrict__ Whh,
                const float* __restrict__ b_ih, const float* __restrict__ b_hh,
                const float* __restrict__ x,    const float* __restrict__ h0,
                float* __restrict__ h_pre, float* __restrict__ gates)
{
    const int gw = (blockIdx.x * 256 + threadIdx.x) >> 6;
    const int lane = threadIdx.x & 63;
    if (gw < HIDDEN) {
        const float* Wr = Wattn + (size_t)gw * 4096;
        float s = 0.f;
        #pragma unroll
        for (int i = 0; i < 8; i++) {
            int c = i * 256 + lane * 4;
            float4 wv = *reinterpret_cast<const float4*>(Wr + c);
            float4 hv = *reinterpret_cast<const float4*>(h0 + c);
            s += wv.x*hv.x + wv.y*hv.y + wv.z*hv.z + wv.w*hv.w;
        }
        s = wave_sum(s);
        if (lane == 0) h_pre[gw] = s + b_attn[gw];
    } else {
        const int j = gw - HIDDEN;
        const float* W1 = Wih + (size_t)j * 2560;        // x part (cols 0..511)
        const float* W2 = Whh + (size_t)j * 2048;
        float s = 0.f;
        #pragma unroll
        for (int i = 0; i < 2; i++) {
            int c = i * 256 + lane * 4;
            float4 wv = *reinterpret_cast<const float4*>(W1 + c);
            float4 xv = *reinterpret_cast<const float4*>(x + c);
            s += wv.x*xv.x + wv.y*xv.y + wv.z*xv.z + wv.w*xv.w;
        }
        #pragma unroll
        for (int i = 0; i < 8; i++) {
            int c = i * 256 + lane * 4;
            float4 wv = *reinterpret_cast<const float4*>(W2 + c);
            float4 hv = *reinterpret_cast<const float4*>(h0 + c);
            s += wv.x*hv.x + wv.y*hv.y + wv.z*hv.z + wv.w*hv.w;
        }
        s = wave_sum(s);
        if (lane == 0) gates[j] = s + b_ih[j] + b_hh[j];
    }
}

// ---------------------------------------------------------------------------
// K2: fused energy GEMM + tanh + v-dot reduction (bf16 inputs).
// C[s,h] = sum_k encbf[s,k] * wbf[h,k]    (NT, MFMA 16x16x32, f32 acc)
// pscore[hb][s] = sum_{h in tile} tanh(C[s,h] + h_pre[h]) * v[h]
// 128x128 tile, BK=64, 4 waves 2x2. LDS linear dest (global_load_lds),
// XOR swizzle byte^=((row&7)<<4) realized by pre-swizzled per-lane source.
__global__ __launch_bounds__(256)
void k_energy2(const unsigned short* __restrict__ encbf,
               const unsigned short* __restrict__ wbf,
               const float* __restrict__ h_pre, const float* __restrict__ v_attn,
               float* __restrict__ pscore)
{
    __shared__ __align__(16) unsigned short As[128 * 64];
    __shared__ __align__(16) unsigned short Bs[128 * 64];
    __shared__ float sh_hv[2][128];
    __shared__ float sh_part[2][128];

    const int tid = threadIdx.x;
    const int hb = blockIdx.x;        // 0..15
    const int sb = blockIdx.y;        // 0..31
    const int s0 = sb * 128, h0 = hb * 128;
    const int wv = tid >> 6, lane = tid & 63;
    const int wm = wv >> 1, wn = wv & 1;

    // Staging: chunk c (0..15) = LDS bytes [c*1024, c*1024+1024), lane gets 16B.
    // off = c*1024 + lane*16; row = c*8 + (lane>>3);
    // source k so that LDS[off] holds swizzled image: k0 = ((lane&7)^(row&7))*8
    const unsigned short* srcA[4];
    const unsigned short* srcB[4];
    #pragma unroll
    for (int i = 0; i < 4; i++) {
        const int c = wv * 4 + i;
        const int row = c * 8 + (lane >> 3);
        const int k0 = ((lane & 7) ^ (row & 7)) * 8;
        srcA[i] = encbf + (size_t)(s0 + row) * 2048 + k0;
        srcB[i] = wbf  + (size_t)(h0 + row) * 2048 + k0;
    }

    f32x4 acc[4][4];
    #pragma unroll
    for (int m = 0; m < 4; m++)
        #pragma unroll
        for (int n = 0; n < 4; n++)
            acc[m][n] = (f32x4){0.f, 0.f, 0.f, 0.f};

    // fragment LDS byte addresses (swizzled): row*128 + ((ks*64+(lane>>4)*16)^((lane&7)<<4))
    const int swz = (lane & 7) << 4;
    const int hi16 = (lane >> 4) * 16;

    for (int kt = 0; kt < 2048; kt += 64) {
        __syncthreads();   // WAR: previous iter's ds_reads done
        #pragma unroll
        for (int i = 0; i < 4; i++) {
            const int c = wv * 4 + i;
            gload16(srcA[i] + kt, &As[c * 512]);
            gload16(srcB[i] + kt, &Bs[c * 512]);
        }
        __syncthreads();   // drains vmcnt (compiler) — loads landed

        frag_t af[2][4], bq[2][4];
        #pragma unroll
        for (int ks = 0; ks < 2; ks++) {
            const int lo = (ks * 64 + hi16) ^ swz;
            #pragma unroll
            for (int m = 0; m < 4; m++) {
                const int rowa = wm * 64 + m * 16 + (lane & 15);
                af[ks][m] = *reinterpret_cast<const frag_t*>(
                    reinterpret_cast<const char*>(As) + rowa * 128 + lo);
                const int rowb = wn * 64 + m * 16 + (lane & 15);
                bq[ks][m] = *reinterpret_cast<const frag_t*>(
                    reinterpret_cast<const char*>(Bs) + rowb * 128 + lo);
            }
        }
        #pragma unroll
        for (int ks = 0; ks < 2; ks++)
            #pragma unroll
            for (int m = 0; m < 4; m++)
                #pragma unroll
                for (int n = 0; n < 4; n++)
                    acc[m][n] = __builtin_amdgcn_mfma_f32_16x16x32_bf16(
                        af[ks][m], bq[ks][n], acc[m][n], 0, 0, 0);
    }

    if (tid < 128) { sh_hv[0][tid] = h_pre[h0 + tid]; sh_hv[1][tid] = v_attn[h0 + tid]; }
    __syncthreads();

    // epilogue: tanh + *v, reduce over h (cols) within the tile
    float ps[4][4];
    #pragma unroll
    for (int m = 0; m < 4; m++)
        #pragma unroll
        for (int r = 0; r < 4; r++) ps[m][r] = 0.f;

    #pragma unroll
    for (int m = 0; m < 4; m++) {
        #pragma unroll
        for (int n = 0; n < 4; n++) {
            const int hc = wn * 64 + n * 16 + (lane & 15);
            const float hp = sh_hv[0][hc], vvv = sh_hv[1][hc];
            #pragma unroll
            for (int r = 0; r < 4; r++) {
                float e = tanhf(acc[m][n][r] + hp);
                ps[m][r] += e * vvv;
            }
        }
    }
    #pragma unroll
    for (int m = 0; m < 4; m++)
        #pragma unroll
        for (int r = 0; r < 4; r++) {
            float p = ps[m][r];
            #pragma unroll
            for (int off = 1; off < 16; off <<= 1) p += __shfl_xor(p, off);
            ps[m][r] = p;
        }
    if ((lane & 15) == 0) {
        const int grp = lane >> 4;
        #pragma unroll
        for (int m = 0; m < 4; m++)
            #pragma unroll
            for (int r = 0; r < 4; r++)
                sh_part[wn][wm * 64 + m * 16 + grp * 4 + r] = ps[m][r];
    }
    __syncthreads();
    if (tid < 128)
        pscore[hb * SEQL + s0 + tid] = sh_part[0][tid] + sh_part[1][tid];
}

// ---------------------------------------------------------------------------
// K3: reduce 16 partial score tiles + softmax over 4096 (one block)
__global__ __launch_bounds__(1024)
void k_softmax(const float* __restrict__ pscore, float* __restrict__ attnw)
{
    __shared__ float red[16];
    __shared__ float bcast;
    const int t = threadIdx.x, wv = t >> 6, lane = t & 63;
    float s[4];
    #pragma unroll
    for (int q = 0; q < 4; q++) {
        const int idx = q * 1024 + t;
        float a = 0.f;
        #pragma unroll
        for (int p = 0; p < 16; p++) a += pscore[p * SEQL + idx];
        s[q] = a;
    }
    float mx = fmaxf(fmaxf(s[0], s[1]), fmaxf(s[2], s[3]));
    #pragma unroll
    for (int off = 32; off; off >>= 1) mx = fmaxf(mx, __shfl_xor(mx, off));
    if (!lane) red[wv] = mx;
    __syncthreads();
    if (t == 0) {
        float m = red[0];
        for (int i = 1; i < 16; i++) m = fmaxf(m, red[i]);
        bcast = m;
    }
    __syncthreads();
    const float bm = bcast;
    float e[4], sum = 0.f;
    #pragma unroll
    for (int q = 0; q < 4; q++) { e[q] = __expf(s[q] - bm); sum += e[q]; }
    #pragma unroll
    for (int off = 32; off; off >>= 1) sum += __shfl_xor(sum, off);
    __syncthreads();
    if (!lane) red[wv] = sum;
    __syncthreads();
    if (t == 0) {
        float m = 0.f;
        for (int i = 0; i < 16; i++) m += red[i];
        bcast = m;
    }
    __syncthreads();
    const float inv = 1.f / bcast;
    #pragma unroll
    for (int q = 0; q < 4; q++) attnw[q * 1024 + t] = e[q] * inv;
}

// ---------------------------------------------------------------------------
// K4: weighted partials: pweight[sb][h] = sum_{s in 64-chunk sb} a[s]*enc[s,h]
__global__ __launch_bounds__(256)
void k_weighted_part(const float* __restrict__ enc, const float* __restrict__ attnw,
                     float* __restrict__ pweight)
{
    const int hb = blockIdx.x & 7, sbk = blockIdx.x >> 3;
    const int h = hb * 256 + threadIdx.x;
    const int sbase = sbk * 64;
    float acc = 0.f;
    for (int s = 0; s < 64; s++)
        acc += attnw[sbase + s] * enc[(size_t)(sbase + s) * HIDDEN + h];
    pweight[sbk * HIDDEN + h] = acc;
}

// K5: reduce 64 partials -> weighted[2048]
__global__ __launch_bounds__(256)
void k_weighted_reduce(const float* __restrict__ pweight, float* __restrict__ weighted)
{
    const int h = blockIdx.x * 256 + threadIdx.x;
    float acc = 0.f;
    #pragma unroll 8
    for (int sb = 0; sb < 64; sb++) acc += pweight[sb * HIDDEN + h];
    weighted[h] = acc;
}

// ---------------------------------------------------------------------------
// K6: gates[j] += W_ih[j, 512:2560] @ weighted
__global__ __launch_bounds__(256)
void k_gates_fin(const float* __restrict__ Wih, const float* __restrict__ weighted,
                 float* __restrict__ gates)
{
    const int j = (blockIdx.x * 256 + threadIdx.x) >> 6;
    const int lane = threadIdx.x & 63;
    const float* Wr = Wih + (size_t)j * 2560 + 512;
    float s = 0.f;
    #pragma unroll
    for (int i = 0; i < 8; i++) {
        int c = i * 256 + lane * 4;
        float4 wv = *reinterpret_cast<const float4*>(Wr + c);
        float4 hv = *reinterpret_cast<const float4*>(weighted + c);
        s += wv.x*hv.x + wv.y*hv.y + wv.z*hv.z + wv.w*hv.w;
    }
    s = wave_sum(s);
    if (lane == 0) gates[j] += s;
}

// ---------------------------------------------------------------------------
// K7: LSTM elementwise. gate order i,f,g,o. writes h_n, c_n into d_out.
__global__ __launch_bounds__(256)
void k_lstm(const float* __restrict__ gates, const float* __restrict__ c0,
            float* __restrict__ dout)
{
    const int t = blockIdx.x * 256 + threadIdx.x;   // 0..2047
    const float gi = gates[t];
    const float gf = gates[2048 + t];
    const float gg = gates[4096 + t];
    const float go = gates[6144 + t];
    const float si = 1.f / (1.f + __expf(-gi));
    const float sf = 1.f / (1.f + __expf(-gf));
    const float so = 1.f / (1.f + __expf(-go));
    const float c = sf * c0[t] + si * tanhf(gg);
    const float h = so * tanhf(c);
    dout[512 + t]  = h;          // h_n
    dout[2560 + t] = c;          // c_n
}

// ---------------------------------------------------------------------------
// K8: out[n] = b_out[n] + W_out[n,0:2048]@h_n + W_out[n,2048:4096]@weighted
__global__ __launch_bounds__(256)
void k_out_gemv(const float* __restrict__ Wout, const float* __restrict__ b_out,
                const float* __restrict__ hn, const float* __restrict__ weighted,
                float* __restrict__ dout)
{
    const int n = (blockIdx.x * 256 + threadIdx.x) >> 6;   // 0..511
    const int lane = threadIdx.x & 63;
    const float* Wr = Wout + (size_t)n * 4096;
    float s = 0.f;
    #pragma unroll
    for (int i = 0; i < 8; i++) {
        int c = i * 256 + lane * 4;
        float4 wv = *reinterpret_cast<const float4*>(Wr + c);
        float4 hv = *reinterpret_cast<const float4*>(hn + c);
        s += wv.x*hv.x + wv.y*hv.y + wv.z*hv.z + wv.w*hv.w;
        float4 wv2 = *reinterpret_cast<const float4*>(Wr + 2048 + c);
        float4 hv2 = *reinterpret_cast<const float4*>(weighted + c);
        s += wv2.x*hv2.x + wv2.y*hv2.y + wv2.z*hv2.z + wv2.w*hv2.w;
    }
    s = wave_sum(s);
    if (lane == 0) dout[n] = s + b_out[n];
}

// ---------------------------------------------------------------------------
extern "C" void kernel_launch(void* const* d_in, const int* in_sizes, int n_in,
                              void* d_out, int out_size, void* d_ws, size_t ws_size,
                              hipStream_t stream)
{
    const float* x        = (const float*)d_in[0];
    const float* ih       = (const float*)d_in[1];
    const float* ic       = (const float*)d_in[2];
    const float* enc      = (const float*)d_in[3];   // [4096,2048]
    const float* Wattn    = (const float*)d_in[4];   // [2048,4096]
    const float* b_attn   = (const float*)d_in[5];
    const float* v_attn   = (const float*)d_in[6];
    const float* Wih      = (const float*)d_in[7];   // [8192,2560]
    const float* Whh      = (const float*)d_in[8];   // [8192,2048]
    const float* b_ih     = (const float*)d_in[9];
    const float* b_hh     = (const float*)d_in[10];
    const float* Wout     = (const float*)d_in[11];  // [512,4096]
    const float* b_out    = (const float*)d_in[12];
    float* dout = (float*)d_out;   // [out 512][h_n 2048][c_n 2048]

    // ws layout: bf16 buffers first, then f32 scratch
    unsigned short* encbf = (unsigned short*)d_ws;                 // 8,388,608
    unsigned short* wbf   = encbf + (size_t)8388608;               // 4,194,304
    float* wsf      = (float*)(wbf + (size_t)4194304);
    float* h_pre    = wsf;                 // 2048
    float* gates    = wsf + 2048;          // 8192
    float* pscore   = wsf + 10240;         // 16*4096
    float* attnw    = wsf + 75776;         // 4096
    float* pweight  = wsf + 79872;         // 64*2048
    float* weighted = wsf + 210944;        // 2048

    k_conv<<<6144, 256, 0, stream>>>(enc, Wattn, encbf, wbf);
    k_pre_gemv<<<2560, 256, 0, stream>>>(Wattn, b_attn, Wih, Whh, b_ih, b_hh,
                                         x, ih, h_pre, gates);
    k_energy2<<<dim3(16, 32), 256, 0, stream>>>(encbf, wbf, h_pre, v_attn, pscore);
    k_softmax<<<1, 1024, 0, stream>>>(pscore, attnw);
    k_weighted_part<<<512, 256, 0, stream>>>(enc, attnw, pweight);
    k_weighted_reduce<<<8, 256, 0, stream>>>(pweight, weighted);
    k_gates_fin<<<2048, 256, 0, stream>>>(Wih, weighted, gates);
    k_lstm<<<8, 256, 0, stream>>>(gates, ic, dout);
    k_out_gemv<<<128, 256, 0, stream>>>(Wout, b_out, dout + 512, weighted, dout);
}